// Round 14
// baseline (252.326 us; speedup 1.0000x reference)
//
#include <hip/hip_runtime.h>
#include <math.h>

#define BB 1024
#define VV 50257
#define EE 128
#define RR 256                      /* rows per block */
#define CC 832                      /* cols per block (13 chunks) */
#define CH 64                       /* cols per staged E-chunk */
#define NCH (CC / CH)               /* 13 chunks */
#define NCB 64                      /* col-blocks: grid = 64x4 = 256 = 1/CU */
#define TAILSTART (VV / CC)         /* 60: cbx >= 60 needs masking */
#define CVTB 2048                   /* cvt blocks inside k_prep */

typedef __bf16 bf16x8 __attribute__((ext_vector_type(8)));
typedef float f32x4 __attribute__((ext_vector_type(4)));
typedef f32x4 __attribute__((aligned(4))) f32x4u;   // 4B-aligned vector ld/st (VV odd)

typedef __attribute__((address_space(3))) void as3_void;
typedef const __attribute__((address_space(1))) void as1_void;

static __device__ __forceinline__ unsigned short f2bf(float f) {
  unsigned int u = __float_as_uint(f);
  u += 0x7fffu + ((u >> 16) & 1u);
  return (unsigned short)(u >> 16);
}

// K1 (fused prep): blocks [0,BB) = per-row early-exit one-hot scan (expected
// read ~half the row); blocks [BB, BB+CVTB) = EMBEDM f32->bf16 convert.
__global__ __launch_bounds__(256) void k_prep(const float* __restrict__ xs,
                                              const float* __restrict__ em,
                                              int* __restrict__ idx,
                                              float* __restrict__ vals,
                                              unsigned short* __restrict__ ebf) {
  const int t = threadIdx.x;
  if (blockIdx.x < BB) {
    const int b = blockIdx.x;
    __shared__ int found;
    const float* row = xs + (size_t)b * VV;
    if (t == 0) {
      found = 0;
      idx[b] = 0; vals[b] = 0.f;                    // safety default (never expected)
      const float tail = row[VV - 1];               // 50257 = 12564*4 + 1
      if (tail != 0.f) { idx[b] = VV - 1; vals[b] = tail; found = 1; }
    }
    __syncthreads();
    if (!found) {
      for (int base = 0; base < 12564; base += 1024) {
#pragma unroll
        for (int j = 0; j < 4; j++) {
          const int i = base + j * 256 + t;
          if (i < 12564) {
            f32x4u v = *(const f32x4u*)(row + i * 4);
            if (v[0] != 0.f || v[1] != 0.f || v[2] != 0.f || v[3] != 0.f) {
#pragma unroll
              for (int c = 0; c < 4; c++)
                if (v[c] != 0.f) { idx[b] = i * 4 + c; vals[b] = v[c]; }
              found = 1;
            }
          }
        }
        __syncthreads();
        if (found) break;
      }
    }
  } else {
    const int total4 = VV * EE / 4;
    const int stride = CVTB * 256;
    for (int i = (blockIdx.x - BB) * 256 + t; i < total4; i += stride) {
      float4 v = ((const float4*)em)[i];
      ushort4 o;
      o.x = f2bf(v.x); o.y = f2bf(v.y); o.z = f2bf(v.z); o.w = f2bf(v.w);
      ((ushort4*)ebf)[i] = o;
    }
  }
}

// K3: y[b] = (val * EMBEDM[idx[b]]) @ metric, stored bf16.
__global__ void k_embed(const float* __restrict__ em, const float* __restrict__ metric,
                        const int* __restrict__ idx, const float* __restrict__ vals,
                        unsigned short* __restrict__ ybf) {
  __shared__ float x[EE];
  const int b = blockIdx.x;
  const int e = threadIdx.x;
  const int row = idx[b];
  const float val = vals[b];
  x[e] = em[(long)row * EE + e] * val;
  __syncthreads();
  float acc = 0.f;
#pragma unroll
  for (int k = 0; k < EE; k++) acc = fmaf(x[k], metric[k * EE + e], acc);
  ybf[b * EE + e] = f2bf(acc);
}

// ---- GEMM scores = Y @ E^T, block = 256 rows x 832 cols, 8 waves.
// R14 change vs R13 (single variable): CC 1024 -> 832, NCB 50 -> 64, so grid
// = 256 blocks = exactly 1 per CU; makespan 16 -> 13 chunks. Inner loop is
// byte-identical to R11/R13 (measured best): Y register/L2-resident, E via
// 2x16KB LDS dbuf, m97 schedule stage(k+1) -> compute(k) -> __syncthreads().

static __device__ __forceinline__ void stageE(const unsigned short* __restrict__ ebf,
                                              char* ldsbuf, int colbase, int w, int lane) {
#pragma unroll
  for (int i = 0; i < 2; i++) {
    const int G = (i * 8 + w) * 64 + lane;   // granule 0..1023 (16B each)
    const int c2 = G >> 4;                   // col within chunk
    const int gc = G & 15;                   // granule within 256B row
    int col = colbase + c2;
    col = col < VV ? col : VV - 1;           // clamp; masked in epilogue
    const char* src = (const char*)(ebf + (size_t)col * EE) + ((gc ^ (c2 & 7)) * 16);
    __builtin_amdgcn_global_load_lds((as1_void*)src,
                                     (as3_void*)(ldsbuf + (i * 8 + w) * 1024), 16, 0, 0);
  }
}

template <bool PASS_B, bool TAIL>
static __device__ __forceinline__ void gemm_body(const unsigned short* __restrict__ ybf,
                                                 const unsigned short* __restrict__ ebf,
                                                 char* __restrict__ ldsE,
                                                 float* __restrict__ pm, float* __restrict__ ps,
                                                 const float* __restrict__ lse,
                                                 float* __restrict__ out) {
  const int cbx = blockIdx.x;
  const int rowbase = blockIdx.y * RR;
  const int w = threadIdx.x >> 6;
  const int l = threadIdx.x & 63;
  const int g = l >> 4;
  const int li = l & 15;
  const int rg = w >> 1;                     // row-group 0..3 (64 rows each)
  const int cg = w & 1;                      // col-group 0..1 (32 cols of each chunk)
  const int cb = cbx * CC;

  // Fully-OOB col-blocks (cbx >= 61): write neutral partials / nothing, exit.
  if (TAIL && cb >= VV) {
    if (!PASS_B) {
      for (int r = threadIdx.x; r < RR; r += 512) {
        pm[(size_t)cbx * BB + rowbase + r] = -INFINITY;
        ps[(size_t)cbx * BB + rowbase + r] = 0.f;
      }
    }
    return;
  }

  // Y: y[rf][kk], rows rowbase + rg*64 + rf*16 + li (compiler may remat from L2).
  bf16x8 y[4][4];
#pragma unroll
  for (int rf = 0; rf < 4; rf++) {
    const bf16x8* yv = (const bf16x8*)(ybf + (size_t)(rowbase + rg * 64 + rf * 16 + li) * EE);
#pragma unroll
    for (int kk = 0; kk < 4; kk++) y[rf][kk] = yv[kk * 4 + g];
  }

  float Lr[4];
  float m[4], s[4];
  if (PASS_B) {
#pragma unroll
    for (int rf = 0; rf < 4; rf++) Lr[rf] = lse[rowbase + rg * 64 + rf * 16 + li];
  } else {
#pragma unroll
    for (int rf = 0; rf < 4; rf++) { m[rf] = -INFINITY; s[rf] = 0.f; }
  }

  stageE(ebf, ldsE, cb, w, l);
  __syncthreads();                           // stage(0) complete for all waves

#pragma unroll 2
  for (int k = 0; k < NCH; k++) {
    if (k + 1 < NCH) stageE(ebf, ldsE + ((k + 1) & 1) * 16384, cb + (k + 1) * CH, w, l);

    const char* cur = ldsE + (k & 1) * 16384;
    bf16x8 afr[2][4];
#pragma unroll
    for (int cf = 0; cf < 2; cf++) {
      const int c2 = cg * 32 + cf * 16 + li;
      const char* ebase = cur + c2 * 256;
#pragma unroll
      for (int kk = 0; kk < 4; kk++)
        afr[cf][kk] = *(const bf16x8*)(ebase + (((kk * 4 + g) ^ (li & 7)) * 16));
    }

    f32x4 acc[4][2];
#pragma unroll
    for (int rf = 0; rf < 4; rf++)
#pragma unroll
      for (int cf = 0; cf < 2; cf++) acc[rf][cf] = (f32x4){0.f, 0.f, 0.f, 0.f};
#pragma unroll
    for (int rf = 0; rf < 4; rf++)
#pragma unroll
      for (int cf = 0; cf < 2; cf++)
#pragma unroll
        for (int kk = 0; kk < 4; kk++)
          acc[rf][cf] = __builtin_amdgcn_mfma_f32_16x16x32_bf16(afr[cf][kk], y[rf][kk],
                                                                acc[rf][cf], 0, 0, 0);

    const int colk = cb + k * CH + cg * 32 + g * 4;   // + cf*16 + r

    if (!PASS_B) {
#pragma unroll
      for (int rf = 0; rf < 4; rf++) {
        float cm = -INFINITY;
#pragma unroll
        for (int cf = 0; cf < 2; cf++)
#pragma unroll
          for (int r = 0; r < 4; r++)
            if (!TAIL || colk + cf * 16 + r < VV) cm = fmaxf(cm, acc[rf][cf][r]);
        const float mn = fmaxf(m[rf], cm);
        if (!TAIL || mn > -INFINITY) {
          float as = s[rf] * __expf(m[rf] - mn);
#pragma unroll
          for (int cf = 0; cf < 2; cf++)
#pragma unroll
            for (int r = 0; r < 4; r++)
              if (!TAIL || colk + cf * 16 + r < VV) as += __expf(acc[rf][cf][r] - mn);
          s[rf] = as; m[rf] = mn;
        }
      }
    } else {
#pragma unroll
      for (int rf = 0; rf < 4; rf++) {
        float* orow = out + (size_t)(rowbase + rg * 64 + rf * 16 + li) * VV;
#pragma unroll
        for (int cf = 0; cf < 2; cf++) {
          const int c = colk + cf * 16;
          if (!TAIL || c + 3 < VV) {
            f32x4 v;
#pragma unroll
            for (int r = 0; r < 4; r++) v[r] = acc[rf][cf][r] - Lr[rf];
            *(f32x4u*)(orow + c) = v;
          } else {
#pragma unroll
            for (int r = 0; r < 4; r++)
              if (c + r < VV) orow[c + r] = acc[rf][cf][r] - Lr[rf];
          }
        }
      }
    }

    __syncthreads();   // stage(k+1) drained (compiler vmcnt) + buf(k) readers done
  }

  if (!PASS_B) {
    // Merge g-groups: lanes l, l^16, l^32, l^48 share the same batch rows.
#pragma unroll
    for (int off = 16; off <= 32; off <<= 1) {
#pragma unroll
      for (int rf = 0; rf < 4; rf++) {
        const float mo = __shfl_xor(m[rf], off);
        const float so = __shfl_xor(s[rf], off);
        const float mn = fmaxf(m[rf], mo);
        float sn;
        if (mn == -INFINITY) sn = 0.f;
        else sn = s[rf] * __expf(m[rf] - mn) + so * __expf(mo - mn);
        m[rf] = mn; s[rf] = sn;
      }
    }
    // Merge the cg wave-pair via LDS scratch (reuse ldsE; loop is done).
    float* scm = (float*)ldsE;                // 512 m + 512 s floats
    float* scs = scm + 512;
    __syncthreads();
    if (l < 16) {
#pragma unroll
      for (int rf = 0; rf < 4; rf++) {
        const int slot = ((rg * 2 + cg) * 4 + rf) * 16 + li;
        scm[slot] = m[rf]; scs[slot] = s[rf];
      }
    }
    __syncthreads();
    const int t = threadIdx.x;
    if (t < 256) {
      const int trg = t >> 6, trf = (t >> 4) & 3, tli = t & 15;
      const int s0 = ((trg * 2 + 0) * 4 + trf) * 16 + tli;
      const int s1 = ((trg * 2 + 1) * 4 + trf) * 16 + tli;
      const float m0 = scm[s0], m1 = scm[s1];
      const float mn = fmaxf(m0, m1);
      float sn;
      if (mn == -INFINITY) sn = 0.f;
      else sn = scs[s0] * __expf(m0 - mn) + scs[s1] * __expf(m1 - mn);
      const int grow = rowbase + trg * 64 + trf * 16 + tli;
      pm[(size_t)cbx * BB + grow] = mn;
      ps[(size_t)cbx * BB + grow] = sn;
    }
  }
}

__global__ __launch_bounds__(512) void k_gemm_a(const unsigned short* __restrict__ ybf,
                                                const unsigned short* __restrict__ ebf,
                                                float* __restrict__ pm,
                                                float* __restrict__ ps) {
  __shared__ char ldsE[2][16384];
  if (blockIdx.x < TAILSTART)
    gemm_body<false, false>(ybf, ebf, ldsE[0], pm, ps, nullptr, nullptr);
  else
    gemm_body<false, true>(ybf, ebf, ldsE[0], pm, ps, nullptr, nullptr);
}

__global__ __launch_bounds__(512) void k_gemm_b(const unsigned short* __restrict__ ybf,
                                                const unsigned short* __restrict__ ebf,
                                                const float* __restrict__ lse,
                                                float* __restrict__ out) {
  __shared__ char ldsE[2][16384];
  if (blockIdx.x < TAILSTART)
    gemm_body<true, false>(ybf, ebf, ldsE[0], nullptr, nullptr, lse, out);
  else
    gemm_body<true, true>(ybf, ebf, ldsE[0], nullptr, nullptr, lse, out);
}

// K5: combine per-col-block partials into lse per row. One wave per row.
__global__ void k_lse(const float* __restrict__ pm, const float* __restrict__ ps,
                      float* __restrict__ lse) {
  const int row = blockIdx.x;
  const int t = threadIdx.x;   // 64 = NCB
  float m = (t < NCB) ? pm[(size_t)t * BB + row] : -INFINITY;
#pragma unroll
  for (int off = 32; off; off >>= 1) m = fmaxf(m, __shfl_xor(m, off));
  float s = (t < NCB) ? ps[(size_t)t * BB + row] * __expf(pm[(size_t)t * BB + row] - m) : 0.f;
#pragma unroll
  for (int off = 32; off; off >>= 1) s += __shfl_xor(s, off);
  if (t == 0) lse[row] = m + logf(s);
}

extern "C" void kernel_launch(void* const* d_in, const int* in_sizes, int n_in,
                              void* d_out, int out_size, void* d_ws, size_t ws_size,
                              hipStream_t stream) {
  const float* xs = (const float*)d_in[0];
  const float* em = (const float*)d_in[1];
  const float* metric = (const float*)d_in[2];
  float* out = (float*)d_out;

  char* w = (char*)d_ws;
  int* idx = (int*)(w + 0);                                   // 4 KB
  float* vals = (float*)(w + 4096);                           // 4 KB
  float* lse = (float*)(w + 8192);                            // 4 KB
  unsigned short* ybf = (unsigned short*)(w + 12288);         // 256 KB
  unsigned short* ebf = (unsigned short*)(w + 12288 + 262144);              // 12.87 MB
  float* pm = (float*)(w + 12288 + 262144 + 12865792);                      // 256 KB
  float* ps = (float*)(w + 12288 + 262144 + 12865792 + (size_t)NCB * BB * 4);

  k_prep<<<BB + CVTB, 256, 0, stream>>>(xs, em, idx, vals, ebf);
  k_embed<<<BB, EE, 0, stream>>>(em, metric, idx, vals, ybf);
  k_gemm_a<<<dim3(NCB, BB / RR), 512, 0, stream>>>(ybf, ebf, pm, ps);
  k_lse<<<BB, 64, 0, stream>>>(pm, ps, lse);
  k_gemm_b<<<dim3(NCB, BB / RR), 512, 0, stream>>>(ybf, ebf, lse, out);
}

// Round 15
// 150.497 us; speedup vs baseline: 1.6766x; 1.6766x over previous
//
#include <hip/hip_runtime.h>
#include <math.h>

#define BB 1024
#define VV 50257
#define EE 128
#define RR 256                      /* rows per block */
#define CC 1024                     /* cols per block */
#define CH 64                       /* cols per staged E-chunk */
#define NCH (CC / CH)               /* 16 chunks */
#define NCB ((VV + CC - 1) / CC)    /* 50 col-blocks */
#define CVTB 2048                   /* cvt blocks inside k_prep */

typedef __bf16 bf16x8 __attribute__((ext_vector_type(8)));
typedef float f32x4 __attribute__((ext_vector_type(4)));
typedef f32x4 __attribute__((aligned(4))) f32x4u;   // 4B-aligned vector ld/st (VV odd)

typedef __attribute__((address_space(3))) void as3_void;
typedef const __attribute__((address_space(1))) void as1_void;

static __device__ __forceinline__ unsigned short f2bf(float f) {
  unsigned int u = __float_as_uint(f);
  u += 0x7fffu + ((u >> 16) & 1u);
  return (unsigned short)(u >> 16);
}

// K1 (fused prep): blocks [0,BB) = per-row early-exit one-hot scan + embed
// (ybf[b] = val * EMBEDM[idx] @ metric); blocks [BB, BB+CVTB) = f32->bf16 cvt.
__global__ __launch_bounds__(256) void k_prep(const float* __restrict__ xs,
                                              const float* __restrict__ em,
                                              const float* __restrict__ metric,
                                              unsigned short* __restrict__ ebf,
                                              unsigned short* __restrict__ ybf) {
  const int t = threadIdx.x;
  if (blockIdx.x < BB) {
    const int b = blockIdx.x;
    __shared__ int found;
    __shared__ int sidx;
    __shared__ float sval;
    __shared__ float x[EE];
    const float* row = xs + (size_t)b * VV;
    if (t == 0) {
      found = 0; sidx = 0; sval = 0.f;              // all-zero row -> ybf row = 0
      const float tail = row[VV - 1];               // 50257 = 12564*4 + 1
      if (tail != 0.f) { sidx = VV - 1; sval = tail; found = 1; }
    }
    __syncthreads();
    if (!found) {
      for (int base = 0; base < 12564; base += 1024) {
#pragma unroll
        for (int j = 0; j < 4; j++) {
          const int i = base + j * 256 + t;
          if (i < 12564) {
            f32x4u v = *(const f32x4u*)(row + i * 4);
            if (v[0] != 0.f || v[1] != 0.f || v[2] != 0.f || v[3] != 0.f) {
#pragma unroll
              for (int c = 0; c < 4; c++)
                if (v[c] != 0.f) { sidx = i * 4 + c; sval = v[c]; }
              found = 1;
            }
          }
        }
        __syncthreads();                            // publishes sidx/sval + found
        if (found) break;
      }
    }
    // Embed: x = val * EMBEDM[idx]; ybf[b] = x @ metric (metric is L2-hot 64KB).
    if (t < EE) x[t] = em[(size_t)sidx * EE + t] * sval;
    __syncthreads();
    if (t < EE) {
      float acc = 0.f;
#pragma unroll
      for (int k = 0; k < EE; k++) acc = fmaf(x[k], metric[k * EE + t], acc);
      ybf[b * EE + t] = f2bf(acc);
    }
  } else {
    const int total4 = VV * EE / 4;
    const int stride = CVTB * 256;
    for (int i = (blockIdx.x - BB) * 256 + t; i < total4; i += stride) {
      float4 v = ((const float4*)em)[i];
      ushort4 o;
      o.x = f2bf(v.x); o.y = f2bf(v.y); o.z = f2bf(v.z); o.w = f2bf(v.w);
      ((ushort4*)ebf)[i] = o;
    }
  }
}

// ---- GEMM scores = Y @ E^T, big tile: block = 256 rows x 1024 cols, 8 waves.
// Byte-identical to R11/R13 (measured best): Y register/L2-resident,
// E streamed through 2x16KB LDS dbuf, m97 schedule: stage(k+1) -> compute(k)
// -> __syncthreads(). No inline asm. DO NOT perturb geometry: R8/R10/R14 all
// regressed via codegen sensitivity (VGPR/remat changes).

static __device__ __forceinline__ void stageE(const unsigned short* __restrict__ ebf,
                                              char* ldsbuf, int colbase, int w, int lane) {
#pragma unroll
  for (int i = 0; i < 2; i++) {
    const int G = (i * 8 + w) * 64 + lane;   // granule 0..1023 (16B each)
    const int c2 = G >> 4;                   // col within chunk
    const int gc = G & 15;                   // granule within 256B row
    int col = colbase + c2;
    col = col < VV ? col : VV - 1;           // clamp; masked in epilogue
    const char* src = (const char*)(ebf + (size_t)col * EE) + ((gc ^ (c2 & 7)) * 16);
    __builtin_amdgcn_global_load_lds((as1_void*)src,
                                     (as3_void*)(ldsbuf + (i * 8 + w) * 1024), 16, 0, 0);
  }
}

template <bool PASS_B, bool TAIL>
static __device__ __forceinline__ void gemm_body(const unsigned short* __restrict__ ybf,
                                                 const unsigned short* __restrict__ ebf,
                                                 char* __restrict__ ldsE,
                                                 float* __restrict__ pm, float* __restrict__ ps,
                                                 const float* __restrict__ lse,
                                                 float* __restrict__ out) {
  const int cbx = blockIdx.x;
  const int rowbase = blockIdx.y * RR;
  const int w = threadIdx.x >> 6;
  const int l = threadIdx.x & 63;
  const int g = l >> 4;
  const int li = l & 15;
  const int rg = w >> 1;                     // row-group 0..3 (64 rows each)
  const int cg = w & 1;                      // col-group 0..1 (32 cols of each chunk)
  const int cb = cbx * CC;

  // Y: y[rf][kk], rows rowbase + rg*64 + rf*16 + li (compiler may remat from L2).
  bf16x8 y[4][4];
#pragma unroll
  for (int rf = 0; rf < 4; rf++) {
    const bf16x8* yv = (const bf16x8*)(ybf + (size_t)(rowbase + rg * 64 + rf * 16 + li) * EE);
#pragma unroll
    for (int kk = 0; kk < 4; kk++) y[rf][kk] = yv[kk * 4 + g];
  }

  float Lr[4];
  float m[4], s[4];
  if (PASS_B) {
#pragma unroll
    for (int rf = 0; rf < 4; rf++) Lr[rf] = lse[rowbase + rg * 64 + rf * 16 + li];
  } else {
#pragma unroll
    for (int rf = 0; rf < 4; rf++) { m[rf] = -INFINITY; s[rf] = 0.f; }
  }

  stageE(ebf, ldsE, cb, w, l);
  __syncthreads();                           // stage(0) complete for all waves

#pragma unroll 2
  for (int k = 0; k < NCH; k++) {
    if (k + 1 < NCH) stageE(ebf, ldsE + ((k + 1) & 1) * 16384, cb + (k + 1) * CH, w, l);

    const char* cur = ldsE + (k & 1) * 16384;
    bf16x8 afr[2][4];
#pragma unroll
    for (int cf = 0; cf < 2; cf++) {
      const int c2 = cg * 32 + cf * 16 + li;
      const char* ebase = cur + c2 * 256;
#pragma unroll
      for (int kk = 0; kk < 4; kk++)
        afr[cf][kk] = *(const bf16x8*)(ebase + (((kk * 4 + g) ^ (li & 7)) * 16));
    }

    f32x4 acc[4][2];
#pragma unroll
    for (int rf = 0; rf < 4; rf++)
#pragma unroll
      for (int cf = 0; cf < 2; cf++) acc[rf][cf] = (f32x4){0.f, 0.f, 0.f, 0.f};
#pragma unroll
    for (int rf = 0; rf < 4; rf++)
#pragma unroll
      for (int cf = 0; cf < 2; cf++)
#pragma unroll
        for (int kk = 0; kk < 4; kk++)
          acc[rf][cf] = __builtin_amdgcn_mfma_f32_16x16x32_bf16(afr[cf][kk], y[rf][kk],
                                                                acc[rf][cf], 0, 0, 0);

    const int colk = cb + k * CH + cg * 32 + g * 4;   // + cf*16 + r

    if (!PASS_B) {
#pragma unroll
      for (int rf = 0; rf < 4; rf++) {
        float cm = -INFINITY;
#pragma unroll
        for (int cf = 0; cf < 2; cf++)
#pragma unroll
          for (int r = 0; r < 4; r++)
            if (!TAIL || colk + cf * 16 + r < VV) cm = fmaxf(cm, acc[rf][cf][r]);
        const float mn = fmaxf(m[rf], cm);
        if (!TAIL || mn > -INFINITY) {
          float as = s[rf] * __expf(m[rf] - mn);
#pragma unroll
          for (int cf = 0; cf < 2; cf++)
#pragma unroll
            for (int r = 0; r < 4; r++)
              if (!TAIL || colk + cf * 16 + r < VV) as += __expf(acc[rf][cf][r] - mn);
          s[rf] = as; m[rf] = mn;
        }
      }
    } else {
#pragma unroll
      for (int rf = 0; rf < 4; rf++) {
        float* orow = out + (size_t)(rowbase + rg * 64 + rf * 16 + li) * VV;
#pragma unroll
        for (int cf = 0; cf < 2; cf++) {
          const int c = colk + cf * 16;
          if (!TAIL || c + 3 < VV) {
            f32x4 v;
#pragma unroll
            for (int r = 0; r < 4; r++) v[r] = acc[rf][cf][r] - Lr[rf];
            *(f32x4u*)(orow + c) = v;
          } else {
#pragma unroll
            for (int r = 0; r < 4; r++)
              if (c + r < VV) orow[c + r] = acc[rf][cf][r] - Lr[rf];
          }
        }
      }
    }

    __syncthreads();   // stage(k+1) drained (compiler vmcnt) + buf(k) readers done
  }

  if (!PASS_B) {
    // Merge g-groups: lanes l, l^16, l^32, l^48 share the same batch rows.
#pragma unroll
    for (int off = 16; off <= 32; off <<= 1) {
#pragma unroll
      for (int rf = 0; rf < 4; rf++) {
        const float mo = __shfl_xor(m[rf], off);
        const float so = __shfl_xor(s[rf], off);
        const float mn = fmaxf(m[rf], mo);
        float sn;
        if (mn == -INFINITY) sn = 0.f;
        else sn = s[rf] * __expf(m[rf] - mn) + so * __expf(mo - mn);
        m[rf] = mn; s[rf] = sn;
      }
    }
    // Merge the cg wave-pair via LDS scratch (reuse ldsE; loop is done).
    float* scm = (float*)ldsE;                // 512 m + 512 s floats
    float* scs = scm + 512;
    __syncthreads();
    if (l < 16) {
#pragma unroll
      for (int rf = 0; rf < 4; rf++) {
        const int slot = ((rg * 2 + cg) * 4 + rf) * 16 + li;
        scm[slot] = m[rf]; scs[slot] = s[rf];
      }
    }
    __syncthreads();
    const int t = threadIdx.x;
    if (t < 256) {
      const int trg = t >> 6, trf = (t >> 4) & 3, tli = t & 15;
      const int s0 = ((trg * 2 + 0) * 4 + trf) * 16 + tli;
      const int s1 = ((trg * 2 + 1) * 4 + trf) * 16 + tli;
      const float m0 = scm[s0], m1 = scm[s1];
      const float mn = fmaxf(m0, m1);
      float sn;
      if (mn == -INFINITY) sn = 0.f;
      else sn = scs[s0] * __expf(m0 - mn) + scs[s1] * __expf(m1 - mn);
      const int grow = rowbase + trg * 64 + trf * 16 + tli;
      pm[(size_t)cbx * BB + grow] = mn;
      ps[(size_t)cbx * BB + grow] = sn;
    }
  }
}

__global__ __launch_bounds__(512) void k_gemm_a(const unsigned short* __restrict__ ybf,
                                                const unsigned short* __restrict__ ebf,
                                                float* __restrict__ pm,
                                                float* __restrict__ ps) {
  __shared__ char ldsE[2][16384];
  if (blockIdx.x < NCB - 1)
    gemm_body<false, false>(ybf, ebf, ldsE[0], pm, ps, nullptr, nullptr);
  else
    gemm_body<false, true>(ybf, ebf, ldsE[0], pm, ps, nullptr, nullptr);
}

__global__ __launch_bounds__(512) void k_gemm_b(const unsigned short* __restrict__ ybf,
                                                const unsigned short* __restrict__ ebf,
                                                const float* __restrict__ lse,
                                                float* __restrict__ out) {
  __shared__ char ldsE[2][16384];
  if (blockIdx.x < NCB - 1)
    gemm_body<true, false>(ybf, ebf, ldsE[0], nullptr, nullptr, lse, out);
  else
    gemm_body<true, true>(ybf, ebf, ldsE[0], nullptr, nullptr, lse, out);
}

// K5: combine per-col-block partials into lse per row. One wave per row.
__global__ void k_lse(const float* __restrict__ pm, const float* __restrict__ ps,
                      float* __restrict__ lse) {
  const int row = blockIdx.x;
  const int t = threadIdx.x;   // 64
  float m = (t < NCB) ? pm[(size_t)t * BB + row] : -INFINITY;
#pragma unroll
  for (int off = 32; off; off >>= 1) m = fmaxf(m, __shfl_xor(m, off));
  float s = (t < NCB) ? ps[(size_t)t * BB + row] * __expf(pm[(size_t)t * BB + row] - m) : 0.f;
#pragma unroll
  for (int off = 32; off; off >>= 1) s += __shfl_xor(s, off);
  if (t == 0) lse[row] = m + logf(s);
}

extern "C" void kernel_launch(void* const* d_in, const int* in_sizes, int n_in,
                              void* d_out, int out_size, void* d_ws, size_t ws_size,
                              hipStream_t stream) {
  const float* xs = (const float*)d_in[0];
  const float* em = (const float*)d_in[1];
  const float* metric = (const float*)d_in[2];
  float* out = (float*)d_out;

  char* w = (char*)d_ws;
  float* lse = (float*)(w + 8192);                            // 4 KB
  unsigned short* ybf = (unsigned short*)(w + 12288);         // 256 KB
  unsigned short* ebf = (unsigned short*)(w + 12288 + 262144);              // 12.87 MB
  float* pm = (float*)(w + 12288 + 262144 + 12865792);                      // 200 KB
  float* ps = (float*)(w + 12288 + 262144 + 12865792 + (size_t)NCB * BB * 4);

  k_prep<<<BB + CVTB, 256, 0, stream>>>(xs, em, metric, ebf, ybf);
  k_gemm_a<<<dim3(NCB, BB / RR), 512, 0, stream>>>(ybf, ebf, pm, ps);
  k_lse<<<BB, 64, 0, stream>>>(pm, ps, lse);
  k_gemm_b<<<dim3(NCB, BB / RR), 512, 0, stream>>>(ybf, ebf, lse, out);
}

// Round 16
// 149.747 us; speedup vs baseline: 1.6850x; 1.0050x over previous
//
#include <hip/hip_runtime.h>
#include <math.h>

#define BB 1024
#define VV 50257
#define EE 128
#define RR 256                      /* rows per block */
#define CC 896                      /* computed cols per block (14 chunks) */
#define CH 64                       /* cols per staged E-chunk */
#define NCH (CC / CH)               /* 14 chunks (even: unroll 2 divides) */
#define NCB 64                      /* col-blocks: grid = 64x4 = 256 = 1/CU */
#define OWN 786                     /* owned cols per block (64*786 >= VV) */
#define CBMAX (VV - CC)             /* 49361: clamp so cb+CC <= VV always */
#define CVTB 2048                   /* cvt blocks inside k_prep */

typedef __bf16 bf16x8 __attribute__((ext_vector_type(8)));
typedef float f32x4 __attribute__((ext_vector_type(4)));
typedef f32x4 __attribute__((aligned(4))) f32x4u;   // 4B-aligned vector ld/st (VV odd)

typedef __attribute__((address_space(3))) void as3_void;
typedef const __attribute__((address_space(1))) void as1_void;

static __device__ __forceinline__ unsigned short f2bf(float f) {
  unsigned int u = __float_as_uint(f);
  u += 0x7fffu + ((u >> 16) & 1u);
  return (unsigned short)(u >> 16);
}

// K1 (fused prep): blocks [0,BB) = per-row early-exit one-hot scan + embed
// (ybf[b] = val * EMBEDM[idx] @ metric); blocks [BB, BB+CVTB) = f32->bf16 cvt.
__global__ __launch_bounds__(256) void k_prep(const float* __restrict__ xs,
                                              const float* __restrict__ em,
                                              const float* __restrict__ metric,
                                              unsigned short* __restrict__ ebf,
                                              unsigned short* __restrict__ ybf) {
  const int t = threadIdx.x;
  if (blockIdx.x < BB) {
    const int b = blockIdx.x;
    __shared__ int found;
    __shared__ int sidx;
    __shared__ float sval;
    __shared__ float x[EE];
    const float* row = xs + (size_t)b * VV;
    if (t == 0) {
      found = 0; sidx = 0; sval = 0.f;              // all-zero row -> ybf row = 0
      const float tail = row[VV - 1];               // 50257 = 12564*4 + 1
      if (tail != 0.f) { sidx = VV - 1; sval = tail; found = 1; }
    }
    __syncthreads();
    if (!found) {
      for (int base = 0; base < 12564; base += 1024) {
#pragma unroll
        for (int j = 0; j < 4; j++) {
          const int i = base + j * 256 + t;
          if (i < 12564) {
            f32x4u v = *(const f32x4u*)(row + i * 4);
            if (v[0] != 0.f || v[1] != 0.f || v[2] != 0.f || v[3] != 0.f) {
#pragma unroll
              for (int c = 0; c < 4; c++)
                if (v[c] != 0.f) { sidx = i * 4 + c; sval = v[c]; }
              found = 1;
            }
          }
        }
        __syncthreads();                            // publishes sidx/sval + found
        if (found) break;
      }
    }
    // Embed: x = val * EMBEDM[idx]; ybf[b] = x @ metric (metric is L2-hot 64KB).
    if (t < EE) x[t] = em[(size_t)sidx * EE + t] * sval;
    __syncthreads();
    if (t < EE) {
      float acc = 0.f;
#pragma unroll
      for (int k = 0; k < EE; k++) acc = fmaf(x[k], metric[k * EE + t], acc);
      ybf[b * EE + t] = f2bf(acc);
    }
  } else {
    const int total4 = VV * EE / 4;
    const int stride = CVTB * 256;
    for (int i = (blockIdx.x - BB) * 256 + t; i < total4; i += stride) {
      float4 v = ((const float4*)em)[i];
      ushort4 o;
      o.x = f2bf(v.x); o.y = f2bf(v.y); o.z = f2bf(v.z); o.w = f2bf(v.w);
      ((ushort4*)ebf)[i] = o;
    }
  }
}

// ---- GEMM scores = Y @ E^T, block = 256 rows x 896 computed cols, 8 waves.
// Grid = 64x4 = 256 blocks = exactly 1/CU (gemm_b is write-bound at CU
// coverage: 200/256 blocks capped it at ~4.9 TB/s). Col-blocks OVERLAP:
// cb = min(cbx*786, VV-896) so every computed col < VV -> pass B epilogue is
// branch-free; pass A masks its online max/sumexp to the disjoint OWNED range
// [cbx*786, +786). Inner loop = proven R11/R13 m97 schedule:
// stage(k+1) -> compute(k) -> __syncthreads(). No inline asm.

static __device__ __forceinline__ void stageE(const unsigned short* __restrict__ ebf,
                                              char* ldsbuf, int colbase, int w, int lane) {
#pragma unroll
  for (int i = 0; i < 2; i++) {
    const int G = (i * 8 + w) * 64 + lane;   // granule 0..1023 (16B each)
    const int c2 = G >> 4;                   // col within chunk
    const int gc = G & 15;                   // granule within 256B row
    int col = colbase + c2;
    col = col < VV ? col : VV - 1;           // safety (never taken: cb+CC <= VV)
    const char* src = (const char*)(ebf + (size_t)col * EE) + ((gc ^ (c2 & 7)) * 16);
    __builtin_amdgcn_global_load_lds((as1_void*)src,
                                     (as3_void*)(ldsbuf + (i * 8 + w) * 1024), 16, 0, 0);
  }
}

template <bool PASS_B>
static __device__ __forceinline__ void gemm_body(const unsigned short* __restrict__ ybf,
                                                 const unsigned short* __restrict__ ebf,
                                                 char* __restrict__ ldsE,
                                                 float* __restrict__ pm, float* __restrict__ ps,
                                                 const float* __restrict__ lse,
                                                 float* __restrict__ out) {
  const int cbx = blockIdx.x;
  const int rowbase = blockIdx.y * RR;
  const int w = threadIdx.x >> 6;
  const int l = threadIdx.x & 63;
  const int g = l >> 4;
  const int li = l & 15;
  const int rg = w >> 1;                     // row-group 0..3 (64 rows each)
  const int cg = w & 1;                      // col-group 0..1 (32 cols of each chunk)
  const int own_lo = cbx * OWN;
  const int own_hi = own_lo + OWN < VV ? own_lo + OWN : VV;
  int cb = own_lo;
  if (cb > CBMAX) cb = CBMAX;                // overlap-clamp: cb+CC <= VV

  // Y: y[rf][kk], rows rowbase + rg*64 + rf*16 + li (compiler may remat from L2).
  bf16x8 y[4][4];
#pragma unroll
  for (int rf = 0; rf < 4; rf++) {
    const bf16x8* yv = (const bf16x8*)(ybf + (size_t)(rowbase + rg * 64 + rf * 16 + li) * EE);
#pragma unroll
    for (int kk = 0; kk < 4; kk++) y[rf][kk] = yv[kk * 4 + g];
  }

  float Lr[4];
  float m[4], s[4];
  if (PASS_B) {
#pragma unroll
    for (int rf = 0; rf < 4; rf++) Lr[rf] = lse[rowbase + rg * 64 + rf * 16 + li];
  } else {
#pragma unroll
    for (int rf = 0; rf < 4; rf++) { m[rf] = -INFINITY; s[rf] = 0.f; }
  }

  stageE(ebf, ldsE, cb, w, l);
  __syncthreads();                           // stage(0) complete for all waves

#pragma unroll 2
  for (int k = 0; k < NCH; k++) {
    if (k + 1 < NCH) stageE(ebf, ldsE + ((k + 1) & 1) * 16384, cb + (k + 1) * CH, w, l);

    const char* cur = ldsE + (k & 1) * 16384;
    bf16x8 afr[2][4];
#pragma unroll
    for (int cf = 0; cf < 2; cf++) {
      const int c2 = cg * 32 + cf * 16 + li;
      const char* ebase = cur + c2 * 256;
#pragma unroll
      for (int kk = 0; kk < 4; kk++)
        afr[cf][kk] = *(const bf16x8*)(ebase + (((kk * 4 + g) ^ (li & 7)) * 16));
    }

    f32x4 acc[4][2];
#pragma unroll
    for (int rf = 0; rf < 4; rf++)
#pragma unroll
      for (int cf = 0; cf < 2; cf++) acc[rf][cf] = (f32x4){0.f, 0.f, 0.f, 0.f};
#pragma unroll
    for (int rf = 0; rf < 4; rf++)
#pragma unroll
      for (int cf = 0; cf < 2; cf++)
#pragma unroll
        for (int kk = 0; kk < 4; kk++)
          acc[rf][cf] = __builtin_amdgcn_mfma_f32_16x16x32_bf16(afr[cf][kk], y[rf][kk],
                                                                acc[rf][cf], 0, 0, 0);

    const int colk = cb + k * CH + cg * 32 + g * 4;   // + cf*16 + r

    if (!PASS_B) {
      // Online max/sumexp over OWNED columns only (overlap cols belong to
      // a neighboring block's slot; counting them twice would corrupt lse).
#pragma unroll
      for (int rf = 0; rf < 4; rf++) {
        float cm = -INFINITY;
#pragma unroll
        for (int cf = 0; cf < 2; cf++)
#pragma unroll
          for (int r = 0; r < 4; r++) {
            const int cv = colk + cf * 16 + r;
            if (cv >= own_lo && cv < own_hi) cm = fmaxf(cm, acc[rf][cf][r]);
          }
        const float mn = fmaxf(m[rf], cm);
        if (mn > -INFINITY) {
          float as = s[rf] * __expf(m[rf] - mn);
#pragma unroll
          for (int cf = 0; cf < 2; cf++)
#pragma unroll
            for (int r = 0; r < 4; r++) {
              const int cv = colk + cf * 16 + r;
              if (cv >= own_lo && cv < own_hi) as += __expf(acc[rf][cf][r] - mn);
            }
          s[rf] = as; m[rf] = mn;
        }
      }
    } else {
      // Branch-free: every computed col < VV; overlap regions get identical
      // values written by two blocks (deterministic).
#pragma unroll
      for (int rf = 0; rf < 4; rf++) {
        float* orow = out + (size_t)(rowbase + rg * 64 + rf * 16 + li) * VV;
#pragma unroll
        for (int cf = 0; cf < 2; cf++) {
          const int c = colk + cf * 16;
          f32x4 v;
#pragma unroll
          for (int r = 0; r < 4; r++) v[r] = acc[rf][cf][r] - Lr[rf];
          *(f32x4u*)(orow + c) = v;
        }
      }
    }

    __syncthreads();   // stage(k+1) drained (compiler vmcnt) + buf(k) readers done
  }

  if (!PASS_B) {
    // Merge g-groups: lanes l, l^16, l^32, l^48 share the same batch rows.
#pragma unroll
    for (int off = 16; off <= 32; off <<= 1) {
#pragma unroll
      for (int rf = 0; rf < 4; rf++) {
        const float mo = __shfl_xor(m[rf], off);
        const float so = __shfl_xor(s[rf], off);
        const float mn = fmaxf(m[rf], mo);
        float sn;
        if (mn == -INFINITY) sn = 0.f;
        else sn = s[rf] * __expf(m[rf] - mn) + so * __expf(mo - mn);
        m[rf] = mn; s[rf] = sn;
      }
    }
    // Merge the cg wave-pair via LDS scratch (reuse ldsE; loop is done).
    float* scm = (float*)ldsE;                // 512 m + 512 s floats
    float* scs = scm + 512;
    __syncthreads();
    if (l < 16) {
#pragma unroll
      for (int rf = 0; rf < 4; rf++) {
        const int slot = ((rg * 2 + cg) * 4 + rf) * 16 + li;
        scm[slot] = m[rf]; scs[slot] = s[rf];
      }
    }
    __syncthreads();
    const int t = threadIdx.x;
    if (t < 256) {
      const int trg = t >> 6, trf = (t >> 4) & 3, tli = t & 15;
      const int s0 = ((trg * 2 + 0) * 4 + trf) * 16 + tli;
      const int s1 = ((trg * 2 + 1) * 4 + trf) * 16 + tli;
      const float m0 = scm[s0], m1 = scm[s1];
      const float mn = fmaxf(m0, m1);
      float sn;
      if (mn == -INFINITY) sn = 0.f;
      else sn = scs[s0] * __expf(m0 - mn) + scs[s1] * __expf(m1 - mn);
      const int grow = rowbase + trg * 64 + trf * 16 + tli;
      pm[(size_t)cbx * BB + grow] = mn;
      ps[(size_t)cbx * BB + grow] = sn;
    }
  }
}

__global__ __launch_bounds__(512) void k_gemm_a(const unsigned short* __restrict__ ybf,
                                                const unsigned short* __restrict__ ebf,
                                                float* __restrict__ pm,
                                                float* __restrict__ ps) {
  __shared__ char ldsE[2][16384];
  gemm_body<false>(ybf, ebf, ldsE[0], pm, ps, nullptr, nullptr);
}

__global__ __launch_bounds__(512) void k_gemm_b(const unsigned short* __restrict__ ybf,
                                                const unsigned short* __restrict__ ebf,
                                                const float* __restrict__ lse,
                                                float* __restrict__ out) {
  __shared__ char ldsE[2][16384];
  gemm_body<true>(ybf, ebf, ldsE[0], nullptr, nullptr, lse, out);
}

// K5: combine per-col-block partials into lse per row. One wave per row.
__global__ void k_lse(const float* __restrict__ pm, const float* __restrict__ ps,
                      float* __restrict__ lse) {
  const int row = blockIdx.x;
  const int t = threadIdx.x;   // 64 = NCB
  float m = pm[(size_t)t * BB + row];
#pragma unroll
  for (int off = 32; off; off >>= 1) m = fmaxf(m, __shfl_xor(m, off));
  float s = ps[(size_t)t * BB + row] * __expf(pm[(size_t)t * BB + row] - m);
#pragma unroll
  for (int off = 32; off; off >>= 1) s += __shfl_xor(s, off);
  if (t == 0) lse[row] = m + logf(s);
}

extern "C" void kernel_launch(void* const* d_in, const int* in_sizes, int n_in,
                              void* d_out, int out_size, void* d_ws, size_t ws_size,
                              hipStream_t stream) {
  const float* xs = (const float*)d_in[0];
  const float* em = (const float*)d_in[1];
  const float* metric = (const float*)d_in[2];
  float* out = (float*)d_out;

  char* w = (char*)d_ws;
  float* lse = (float*)(w + 8192);                            // 4 KB
  unsigned short* ybf = (unsigned short*)(w + 12288);         // 256 KB
  unsigned short* ebf = (unsigned short*)(w + 12288 + 262144);              // 12.87 MB
  float* pm = (float*)(w + 12288 + 262144 + 12865792);                      // 256 KB
  float* ps = (float*)(w + 12288 + 262144 + 12865792 + (size_t)NCB * BB * 4);

  k_prep<<<BB + CVTB, 256, 0, stream>>>(xs, em, metric, ebf, ybf);
  k_gemm_a<<<dim3(NCB, BB / RR), 512, 0, stream>>>(ybf, ebf, pm, ps);
  k_lse<<<BB, 64, 0, stream>>>(pm, ps, lse);
  k_gemm_b<<<dim3(NCB, BB / RR), 512, 0, stream>>>(ybf, ebf, lse, out);
}